// Round 9
// baseline (239.689 us; speedup 1.0000x reference)
//
#include <hip/hip_runtime.h>
#include <math.h>

#define D_MODEL 1024
#define NHEAD 16
#define HD 64
#define SEQ 2048
#define BATCH 2
#define MTOT (BATCH * SEQ)  // 4096

typedef __attribute__((ext_vector_type(8))) short bf16x8;
typedef __attribute__((ext_vector_type(4))) float f32x4;

__device__ __forceinline__ unsigned short f2bf(float f) {
    unsigned int u = __float_as_uint(f);
    u += 0x7FFF + ((u >> 16) & 1);  // round-to-nearest-even
    return (unsigned short)(u >> 16);
}

__device__ __forceinline__ unsigned int pk2bf(float a, float b) {
    return (unsigned int)f2bf(a) | ((unsigned int)f2bf(b) << 16);
}

// async global->LDS, 16B per lane. lds must be the wave-uniform chunk base:
// HW writes lane's 16B to base + lane*16 (guide §5 caveat).
__device__ __forceinline__ void async16(unsigned short* lds, const unsigned short* g) {
    __builtin_amdgcn_global_load_lds(
        (const __attribute__((address_space(1))) unsigned int*)g,
        (__attribute__((address_space(3))) unsigned int*)lds, 16, 0, 0);
}

// raw barrier: no compiler-forced vmcnt(0) drain (unlike __syncthreads);
// "memory" clobber = compile-time fence so LDS/DMA ops don't cross.
#define BAR() asm volatile("s_barrier" ::: "memory")

// ---------------------------------------------------------------------------
// Fused prep: blocks [0,4096) convert x fp32->bf16; blocks [4096,8192)
// transpose the 4 weights W[k][n] fp32 -> Wt[n][k] bf16.
// ---------------------------------------------------------------------------
__global__ __launch_bounds__(256) void prep(const float* __restrict__ x,
                                            unsigned short* __restrict__ xb,
                                            const float* __restrict__ W0,
                                            const float* __restrict__ W1,
                                            const float* __restrict__ W2,
                                            const float* __restrict__ W3,
                                            unsigned short* __restrict__ Wt) {
    const int bid = blockIdx.x;
    const int tid = threadIdx.x;
    if (bid < 4096) {
        const int i = (bid * 256 + tid) * 4;
        float4 v = *(const float4*)(x + i);
        uint2 pk;
        pk.x = pk2bf(v.x, v.y);
        pk.y = pk2bf(v.z, v.w);
        *(uint2*)(xb + i) = pk;
    } else {
        __shared__ float T[32][33];
        const int t = bid - 4096;
        const int z = t >> 10, rem = t & 1023;
        const int n0 = (rem & 31) * 32, k0 = (rem >> 5) * 32;
        const float* W = (z == 0) ? W0 : (z == 1) ? W1 : (z == 2) ? W2 : W3;
        unsigned short* out = Wt + (size_t)z * D_MODEL * D_MODEL;
        const int tx = tid & 31, ty = tid >> 5;
#pragma unroll
        for (int i = 0; i < 4; ++i)
            T[ty + 8 * i][tx] = W[(size_t)(k0 + ty + 8 * i) * D_MODEL + n0 + tx];
        __syncthreads();
#pragma unroll
        for (int i = 0; i < 4; ++i)
            out[(size_t)(n0 + ty + 8 * i) * D_MODEL + k0 + tx] = f2bf(T[tx][ty + 8 * i]);
    }
}

// ---------------------------------------------------------------------------
// bf16 MFMA GEMM, global_load_lds staging (width=16, unpadded LDS).
// 128x128 tile / block, BK=64, 256 threads = 4 waves (2x2), each wave 64x64.
// MODE 0: z selects Wq/Wk/Wv; writes Q (pre-scaled by 0.125*log2e), K ->
//         [B,H,N,64] and V -> V^T [B,H,64,N]; ALL epilogues LDS-staged with
//         fully-coalesced 16B stores.
// MODE 1: fp32 row-major output.
// ---------------------------------------------------------------------------
template <int MODE>
__global__ __launch_bounds__(256) void gemm_mfma(const unsigned short* __restrict__ A,
                                                 const unsigned short* __restrict__ Wt,
                                                 unsigned short* __restrict__ q,
                                                 unsigned short* __restrict__ k,
                                                 unsigned short* __restrict__ vt,
                                                 float* __restrict__ outf) {
    __shared__ unsigned short SM[16384];  // As = SM[0:8192), Bs = SM[8192:16384)
    const int tid = threadIdx.x;
    const int z = blockIdx.z;
    const unsigned short* B = Wt + (size_t)z * D_MODEL * D_MODEL;
    const int m0 = blockIdx.y * 128, n0 = blockIdx.x * 128;
    const int wave = tid >> 6, lane = tid & 63;
    const int quad = lane >> 4, l16 = lane & 15;
    const int wm = wave & 1, wn = wave >> 1;

    f32x4 acc[4][4];
#pragma unroll
    for (int mt = 0; mt < 4; ++mt)
#pragma unroll
        for (int nt = 0; nt < 4; ++nt)
            acc[mt][nt] = (f32x4){0.f, 0.f, 0.f, 0.f};

    for (int k0 = 0; k0 < D_MODEL; k0 += 64) {
        __syncthreads();  // previous iteration's reads done
#pragma unroll
        for (int i = 0; i < 4; ++i) {
            const int c = i * 256 + tid;
            const int r = c >> 3, cc = (c & 7) * 8;
            const int cbase = i * 256 + wave * 64;  // wave-uniform chunk base
            async16(SM + cbase * 8, A + (size_t)(m0 + r) * D_MODEL + k0 + cc);
            async16(SM + 8192 + cbase * 8, B + (size_t)(n0 + r) * D_MODEL + k0 + cc);
        }
        __syncthreads();  // drains vmcnt per barrier semantics
#pragma unroll
        for (int ks = 0; ks < 2; ++ks) {
            bf16x8 af[4], bfr[4];
#pragma unroll
            for (int mt = 0; mt < 4; ++mt)
                af[mt] = *(const bf16x8*)&SM[(wm * 64 + mt * 16 + l16) * 64 + ks * 32 + quad * 8];
#pragma unroll
            for (int nt = 0; nt < 4; ++nt)
                bfr[nt] = *(const bf16x8*)&SM[8192 + (wn * 64 + nt * 16 + l16) * 64 + ks * 32 + quad * 8];
#pragma unroll
            for (int mt = 0; mt < 4; ++mt)
#pragma unroll
                for (int nt = 0; nt < 4; ++nt)
                    acc[mt][nt] = __builtin_amdgcn_mfma_f32_16x16x32_bf16(
                        af[mt], bfr[nt], acc[mt][nt], 0, 0, 0);
        }
    }

    if (MODE == 1) {
#pragma unroll
        for (int mt = 0; mt < 4; ++mt)
#pragma unroll
            for (int nt = 0; nt < 4; ++nt)
#pragma unroll
                for (int reg = 0; reg < 4; ++reg) {
                    const int m = m0 + wm * 64 + mt * 16 + quad * 4 + reg;
                    const int n = n0 + wn * 64 + nt * 16 + l16;
                    outf[(size_t)m * D_MODEL + n] = acc[mt][nt][reg];
                }
    } else if (z < 2) {
        // Q/K epilogue: stage [tok][d] in LDS (2 heads side by side, row
        // stride 128), then fully-coalesced uint4 stores. 2 passes (wm).
        // Q gets softmax scale folded in (exp2 domain): 0.125 * log2(e).
        const float qsc = (z == 0) ? 0.18033688011112042f : 1.0f;
        unsigned short* dst = (z == 0) ? q : k;
        const int bb = m0 >> 11;
        const int tok0 = m0 & (SEQ - 1);
        const int h0 = n0 >> 6;  // 2 heads per 128-col tile
#pragma unroll
        for (int pass = 0; pass < 2; ++pass) {
            __syncthreads();  // SM free (K-loop or previous pass done)
            if (wm == pass) {
#pragma unroll
                for (int mt = 0; mt < 4; ++mt)
#pragma unroll
                    for (int nt = 0; nt < 4; ++nt)
#pragma unroll
                        for (int reg = 0; reg < 4; ++reg) {
                            const int r = mt * 16 + quad * 4 + reg;
                            const int cc = wn * 64 + nt * 16 + l16;
                            SM[r * 128 + cc] = f2bf(acc[mt][nt][reg] * qsc);
                        }
            }
            __syncthreads();
#pragma unroll
            for (int it = 0; it < 4; ++it) {
                const int cix = it * 256 + tid;
                const int r = cix >> 4, g = cix & 15;
                const int hh = g >> 3, d8 = g & 7;
                uint4 val = *(const uint4*)&SM[r * 128 + g * 8];
                *(uint4*)(dst + (((size_t)bb * NHEAD + h0 + hh) * SEQ +
                                 tok0 + pass * 64 + r) * HD + d8 * 8) = val;
            }
        }
    } else {
        // V^T epilogue: stage [d][m] in LDS (pad 136), then coalesced stores.
        const int bb = m0 >> 11, tok0 = m0 & (SEQ - 1);
#pragma unroll
        for (int pass = 0; pass < 2; ++pass) {
            __syncthreads();  // SM free (K-loop or previous pass done)
            if (wn == pass) {
#pragma unroll
                for (int mt = 0; mt < 4; ++mt)
#pragma unroll
                    for (int nt = 0; nt < 4; ++nt) {
                        const int d = nt * 16 + l16;
                        const int m = wm * 64 + mt * 16 + quad * 4;
                        uint2 w;
                        w.x = pk2bf(acc[mt][nt][0], acc[mt][nt][1]);
                        w.y = pk2bf(acc[mt][nt][2], acc[mt][nt][3]);
                        *(uint2*)&SM[d * 136 + m] = w;
                    }
            }
            __syncthreads();
            const int h = (n0 >> 6) + pass;
#pragma unroll
            for (int it = 0; it < 4; ++it) {
                const int c = it * 256 + tid;
                const int d = c >> 4, mc = (c & 15) * 8;
                uint4 val = *(const uint4*)&SM[d * 136 + mc];
                *(uint4*)(vt + (((size_t)bb * NHEAD + h) * HD + d) * SEQ + tok0 + mc) = val;
            }
        }
    }
}

// ---------------------------------------------------------------------------
// MFMA flash attention (causal), 4 waves / 128-row q-tile, K+V double-buffered
// cp.async pipeline, 2 raw barriers per iteration.
// Grid (NHEAD, 16, BATCH); p = 15 - blockIdx.y (heavy blocks dispatch first).
// All 512 blocks fit co-resident (48 KB LDS -> 3 blocks/CU capacity).
// Wave w owns q-rows [p*128 + 32w, +32); waves 0/1 skip compute on the final
// block iteration (their causal range ends one K-tile earlier).
// Kb/Vb XOR-swizzled in 16B granules (phys = log ^ (row&7)) on both the DMA
// source and ds_read addresses; Ps XOR-swizzled unpadded [128][64].
// ---------------------------------------------------------------------------
__global__ __launch_bounds__(256) void attn_mfma(const unsigned short* __restrict__ Q,
                                                 const unsigned short* __restrict__ K,
                                                 const unsigned short* __restrict__ VT,
                                                 unsigned short* __restrict__ ctx) {
    __shared__ unsigned short Kb[2][4096];  // [buf][64 k-rows x 64 d] swizzled
    __shared__ unsigned short Vb[2][4096];  // [buf][64 d x 64 kcol] swizzled
    __shared__ unsigned short Ps[128 * 64]; // wave-private 32-row bands, swizzled
    const int tid = threadIdx.x;
    const int wave = tid >> 6, lane = tid & 63;
    const int quad = lane >> 4, l16 = lane & 15;
    const int h = blockIdx.x, b = blockIdx.z;
    const int p = 15 - (int)blockIdx.y;  // heavy-first
    const int row0 = p * 128 + wave * 32;
    const unsigned short* Qp = Q + ((size_t)b * NHEAD + h) * SEQ * HD;
    const unsigned short* Kp = K + ((size_t)b * NHEAD + h) * SEQ * HD;
    const unsigned short* Vp = VT + ((size_t)b * NHEAD + h) * HD * SEQ;
    unsigned short* Pw = Ps + wave * 2048;

    // DMA swizzle: chunk c covers rows c*8+srow; lane's 16B granule sgr
    const int srow = lane >> 3;
    const int sgr = ((lane & 7) ^ srow) * 8;
    const int sw8 = l16 & 7;  // read-side swizzle key (row & 7)

    bf16x8 bQ[2][2];  // Q as B-operand: [q-frag][ks]
#pragma unroll
    for (int f = 0; f < 2; ++f)
#pragma unroll
        for (int ks = 0; ks < 2; ++ks)
            bQ[f][ks] = *(const bf16x8*)(Qp +
                (size_t)(row0 + f * 16 + l16) * HD + ks * 32 + quad * 8);

    f32x4 o[4][2];    // O^T accumulators: [d-tile][q-frag]
    float ps[2] = {0.f, 0.f};
#pragma unroll
    for (int nt = 0; nt < 4; ++nt)
#pragma unroll
        for (int f = 0; f < 2; ++f)
            o[nt][f] = (f32x4){0.f, 0.f, 0.f, 0.f};

    const int ktmax_w = (row0 + 31) >> 6;  // wave causal limit (2p or 2p+1)
    const int ktmax_blk = 2 * p + 1;

    // prologue: K(0),V(0) -> buf 0; each wave loads chunks {2w, 2w+1}
#pragma unroll
    for (int i = 0; i < 2; ++i) {
        const int c = wave * 2 + i;
        async16(&Kb[0][c * 512], Kp + (size_t)(c * 8 + srow) * HD + sgr);
    }
#pragma unroll
    for (int i = 0; i < 2; ++i) {
        const int c = wave * 2 + i;
        async16(&Vb[0][c * 512], Vp + (size_t)(c * 8 + srow) * SEQ + sgr);
    }

    for (int kt = 0; kt <= ktmax_blk; ++kt) {
        const int cur = kt & 1;
        BAR();  // all waves done computing (kt-1) -> buf^1 safe to overwrite

        if (kt < ktmax_blk) {
#pragma unroll
            for (int i = 0; i < 2; ++i) {
                const int c = wave * 2 + i;
                async16(&Kb[cur ^ 1][c * 512],
                        Kp + (size_t)((kt + 1) * 64 + c * 8 + srow) * HD + sgr);
            }
#pragma unroll
            for (int i = 0; i < 2; ++i) {
                const int c = wave * 2 + i;
                async16(&Vb[cur ^ 1][c * 512],
                        Vp + (size_t)(c * 8 + srow) * SEQ + (kt + 1) * 64 + sgr);
            }
            // outstanding: K(kt)2+V(kt)2 old, K(kt+1)2+V(kt+1)2 new -> wait old
            asm volatile("s_waitcnt vmcnt(4)" ::: "memory");
        } else {
            asm volatile("s_waitcnt vmcnt(0)" ::: "memory");
        }
        BAR();  // all waves' K(kt),V(kt) DMA complete

        if (kt <= ktmax_w) {
            // ---- S^T = K Q^T from Kb[cur] (swizzled reads) ----
            f32x4 sT[4][2];
#pragma unroll
            for (int mt = 0; mt < 4; ++mt) {
                const int krow = mt * 16 + l16;
                bf16x8 aK0 = *(const bf16x8*)&Kb[cur][krow * 64 + ((0 + quad) ^ sw8) * 8];
                bf16x8 aK1 = *(const bf16x8*)&Kb[cur][krow * 64 + ((4 + quad) ^ sw8) * 8];
#pragma unroll
                for (int f = 0; f < 2; ++f) {
                    sT[mt][f] = __builtin_amdgcn_mfma_f32_16x16x32_bf16(
                        aK0, bQ[f][0], (f32x4){0.f, 0.f, 0.f, 0.f}, 0, 0, 0);
                    sT[mt][f] = __builtin_amdgcn_mfma_f32_16x16x32_bf16(
                        aK1, bQ[f][1], sT[mt][f], 0, 0, 0);
                }
            }

            // ---- exp2 + causal mask + swizzled packed P write + row-sum ----
            const bool diag = (kt == ktmax_w);
#pragma unroll
            for (int mt = 0; mt < 4; ++mt)
#pragma unroll
                for (int f = 0; f < 2; ++f) {
                    float pv[4];
#pragma unroll
                    for (int reg = 0; reg < 4; ++reg)
                        pv[reg] = exp2f(sT[mt][f][reg]);
                    if (diag) {
                        const int kb = kt * 64 + mt * 16 + quad * 4;
                        const int qg = row0 + f * 16 + l16;
#pragma unroll
                        for (int reg = 0; reg < 4; ++reg)
                            pv[reg] = (kb + reg > qg) ? 0.f : pv[reg];
                    }
                    ps[f] += (pv[0] + pv[1]) + (pv[2] + pv[3]);
                    uint2 w;
                    w.x = pk2bf(pv[0], pv[1]);
                    w.y = pk2bf(pv[2], pv[3]);
                    const int gph = ((mt * 2 + (quad >> 1)) ^ sw8);
                    *(uint2*)&Pw[(f * 16 + l16) * 64 + gph * 8 + (quad & 1) * 4] = w;
                }

            // P back in B-layout (wave-private rows; same-wave DS order)
            bf16x8 bP[2][2];
#pragma unroll
            for (int f = 0; f < 2; ++f)
#pragma unroll
                for (int ks = 0; ks < 2; ++ks)
                    bP[f][ks] = *(const bf16x8*)&Pw[(f * 16 + l16) * 64 +
                                                    ((ks * 4 + quad) ^ sw8) * 8];

            // ---- O^T += V^T P^T from Vb[cur] (swizzled reads) ----
#pragma unroll
            for (int nt = 0; nt < 4; ++nt) {
                const int drow = nt * 16 + l16;
                bf16x8 aV0 = *(const bf16x8*)&Vb[cur][drow * 64 + ((0 + quad) ^ sw8) * 8];
                bf16x8 aV1 = *(const bf16x8*)&Vb[cur][drow * 64 + ((4 + quad) ^ sw8) * 8];
#pragma unroll
                for (int f = 0; f < 2; ++f) {
                    o[nt][f] = __builtin_amdgcn_mfma_f32_16x16x32_bf16(
                        aV0, bP[f][0], o[nt][f], 0, 0, 0);
                    o[nt][f] = __builtin_amdgcn_mfma_f32_16x16x32_bf16(
                        aV1, bP[f][1], o[nt][f], 0, 0, 0);
                }
            }
        }
    }

    // row-sum reduce across quads (q-row lives in l16; partials in quads)
    float inv[2];
#pragma unroll
    for (int f = 0; f < 2; ++f) {
        ps[f] += __shfl_xor(ps[f], 16);
        ps[f] += __shfl_xor(ps[f], 32);
        inv[f] = 1.f / ps[f];
    }

    // ctx store: token = row0 + f*16 + l16; cols consecutive -> packed 8B
#pragma unroll
    for (int nt = 0; nt < 4; ++nt)
#pragma unroll
        for (int f = 0; f < 2; ++f) {
            const int tok = row0 + f * 16 + l16;
            const int col = h * HD + nt * 16 + quad * 4;
            uint2 w;
            w.x = pk2bf(o[nt][f][0] * inv[f], o[nt][f][1] * inv[f]);
            w.y = pk2bf(o[nt][f][2] * inv[f], o[nt][f][3] * inv[f]);
            *(uint2*)(ctx + ((size_t)b * SEQ + tok) * D_MODEL + col) = w;
        }
}

extern "C" void kernel_launch(void* const* d_in, const int* in_sizes, int n_in,
                              void* d_out, int out_size, void* d_ws, size_t ws_size,
                              hipStream_t stream) {
    const float* x  = (const float*)d_in[0];
    const float* Wq = (const float*)d_in[1];
    const float* Wk = (const float*)d_in[2];
    const float* Wv = (const float*)d_in[3];
    const float* Wo = (const float*)d_in[4];
    float* out = (float*)d_out;

    unsigned short* ws = (unsigned short*)d_ws;
    const size_t T = (size_t)MTOT * D_MODEL;  // 4,194,304 elements
    unsigned short* xb  = ws;                 // [4096,1024] bf16
    unsigned short* Wt  = ws + T;             // 4 x [1024,1024] bf16 (W^T)
    unsigned short* q   = ws + 2 * T;         // [B,H,N,64]  (pre-scaled)
    unsigned short* k   = ws + 3 * T;         // [B,H,N,64]
    unsigned short* vt  = ws + 4 * T;         // [B,H,64,N]
    unsigned short* ctx = ws + 5 * T;         // [4096,1024]

    prep<<<dim3(8192), dim3(256), 0, stream>>>(x, xb, Wq, Wk, Wv, Wo, Wt);

    gemm_mfma<0><<<dim3(8, 32, 3), dim3(256), 0, stream>>>(xb, Wt, q, k, vt, nullptr);

    attn_mfma<<<dim3(NHEAD, 16, BATCH), dim3(256), 0, stream>>>(q, k, vt, ctx);

    gemm_mfma<1><<<dim3(8, 32, 1), dim3(256), 0, stream>>>(ctx, Wt + 3 * (size_t)D_MODEL * D_MODEL,
                                                           nullptr, nullptr, nullptr, out);
}

// Round 10
// 222.409 us; speedup vs baseline: 1.0777x; 1.0777x over previous
//
#include <hip/hip_runtime.h>
#include <math.h>

#define D_MODEL 1024
#define NHEAD 16
#define HD 64
#define SEQ 2048
#define BATCH 2
#define MTOT (BATCH * SEQ)  // 4096

typedef __attribute__((ext_vector_type(8))) short bf16x8;
typedef __attribute__((ext_vector_type(4))) float f32x4;

__device__ __forceinline__ unsigned short f2bf(float f) {
    unsigned int u = __float_as_uint(f);
    u += 0x7FFF + ((u >> 16) & 1);  // round-to-nearest-even
    return (unsigned short)(u >> 16);
}

__device__ __forceinline__ unsigned int pk2bf(float a, float b) {
    return (unsigned int)f2bf(a) | ((unsigned int)f2bf(b) << 16);
}

// async global->LDS, 16B per lane. lds must be the wave-uniform chunk base:
// HW writes lane's 16B to base + lane*16 (guide §5 caveat).
__device__ __forceinline__ void async16(unsigned short* lds, const unsigned short* g) {
    __builtin_amdgcn_global_load_lds(
        (const __attribute__((address_space(1))) unsigned int*)g,
        (__attribute__((address_space(3))) unsigned int*)lds, 16, 0, 0);
}

// ---------------------------------------------------------------------------
// Fused prep: blocks [0,4096) convert x fp32->bf16; blocks [4096,8192)
// transpose the 4 weights W[k][n] fp32 -> Wt[n][k] bf16.
// ---------------------------------------------------------------------------
__global__ __launch_bounds__(256) void prep(const float* __restrict__ x,
                                            unsigned short* __restrict__ xb,
                                            const float* __restrict__ W0,
                                            const float* __restrict__ W1,
                                            const float* __restrict__ W2,
                                            const float* __restrict__ W3,
                                            unsigned short* __restrict__ Wt) {
    const int bid = blockIdx.x;
    const int tid = threadIdx.x;
    if (bid < 4096) {
        const int i = (bid * 256 + tid) * 4;
        float4 v = *(const float4*)(x + i);
        uint2 pk;
        pk.x = pk2bf(v.x, v.y);
        pk.y = pk2bf(v.z, v.w);
        *(uint2*)(xb + i) = pk;
    } else {
        __shared__ float T[32][33];
        const int t = bid - 4096;
        const int z = t >> 10, rem = t & 1023;
        const int n0 = (rem & 31) * 32, k0 = (rem >> 5) * 32;
        const float* W = (z == 0) ? W0 : (z == 1) ? W1 : (z == 2) ? W2 : W3;
        unsigned short* out = Wt + (size_t)z * D_MODEL * D_MODEL;
        const int tx = tid & 31, ty = tid >> 5;
#pragma unroll
        for (int i = 0; i < 4; ++i)
            T[ty + 8 * i][tx] = W[(size_t)(k0 + ty + 8 * i) * D_MODEL + n0 + tx];
        __syncthreads();
#pragma unroll
        for (int i = 0; i < 4; ++i)
            out[(size_t)(n0 + ty + 8 * i) * D_MODEL + k0 + tx] = f2bf(T[tx][ty + 8 * i]);
    }
}

// ---------------------------------------------------------------------------
// bf16 MFMA GEMM, global_load_lds staging (width=16, unpadded LDS).
// 128x128 tile / block, BK=64, 256 threads = 4 waves (2x2), each wave 64x64.
// MODE 0: z selects Wq/Wk/Wv; writes Q (pre-scaled by 0.125*log2e), K ->
//         [B,H,N,64] and V -> V^T [B,H,64,N]; ALL epilogues LDS-staged with
//         fully-coalesced 16B stores.
// MODE 1: fp32 row-major output.
// ---------------------------------------------------------------------------
template <int MODE>
__global__ __launch_bounds__(256) void gemm_mfma(const unsigned short* __restrict__ A,
                                                 const unsigned short* __restrict__ Wt,
                                                 unsigned short* __restrict__ q,
                                                 unsigned short* __restrict__ k,
                                                 unsigned short* __restrict__ vt,
                                                 float* __restrict__ outf) {
    __shared__ unsigned short SM[16384];  // As = SM[0:8192), Bs = SM[8192:16384)
    const int tid = threadIdx.x;
    const int z = blockIdx.z;
    const unsigned short* B = Wt + (size_t)z * D_MODEL * D_MODEL;
    const int m0 = blockIdx.y * 128, n0 = blockIdx.x * 128;
    const int wave = tid >> 6, lane = tid & 63;
    const int quad = lane >> 4, l16 = lane & 15;
    const int wm = wave & 1, wn = wave >> 1;

    f32x4 acc[4][4];
#pragma unroll
    for (int mt = 0; mt < 4; ++mt)
#pragma unroll
        for (int nt = 0; nt < 4; ++nt)
            acc[mt][nt] = (f32x4){0.f, 0.f, 0.f, 0.f};

    for (int k0 = 0; k0 < D_MODEL; k0 += 64) {
        __syncthreads();  // previous iteration's reads done
#pragma unroll
        for (int i = 0; i < 4; ++i) {
            const int c = i * 256 + tid;
            const int r = c >> 3, cc = (c & 7) * 8;
            const int cbase = i * 256 + wave * 64;  // wave-uniform chunk base
            async16(SM + cbase * 8, A + (size_t)(m0 + r) * D_MODEL + k0 + cc);
            async16(SM + 8192 + cbase * 8, B + (size_t)(n0 + r) * D_MODEL + k0 + cc);
        }
        __syncthreads();  // drains vmcnt per barrier semantics
#pragma unroll
        for (int ks = 0; ks < 2; ++ks) {
            bf16x8 af[4], bfr[4];
#pragma unroll
            for (int mt = 0; mt < 4; ++mt)
                af[mt] = *(const bf16x8*)&SM[(wm * 64 + mt * 16 + l16) * 64 + ks * 32 + quad * 8];
#pragma unroll
            for (int nt = 0; nt < 4; ++nt)
                bfr[nt] = *(const bf16x8*)&SM[8192 + (wn * 64 + nt * 16 + l16) * 64 + ks * 32 + quad * 8];
#pragma unroll
            for (int mt = 0; mt < 4; ++mt)
#pragma unroll
                for (int nt = 0; nt < 4; ++nt)
                    acc[mt][nt] = __builtin_amdgcn_mfma_f32_16x16x32_bf16(
                        af[mt], bfr[nt], acc[mt][nt], 0, 0, 0);
        }
    }

    if (MODE == 1) {
#pragma unroll
        for (int mt = 0; mt < 4; ++mt)
#pragma unroll
            for (int nt = 0; nt < 4; ++nt)
#pragma unroll
                for (int reg = 0; reg < 4; ++reg) {
                    const int m = m0 + wm * 64 + mt * 16 + quad * 4 + reg;
                    const int n = n0 + wn * 64 + nt * 16 + l16;
                    outf[(size_t)m * D_MODEL + n] = acc[mt][nt][reg];
                }
    } else if (z < 2) {
        // Q/K epilogue: stage [tok][d] in LDS (2 heads side by side, row
        // stride 128), then fully-coalesced uint4 stores. 2 passes (wm).
        // Q gets softmax scale folded in (exp2 domain): 0.125 * log2(e).
        const float qsc = (z == 0) ? 0.18033688011112042f : 1.0f;
        unsigned short* dst = (z == 0) ? q : k;
        const int bb = m0 >> 11;
        const int tok0 = m0 & (SEQ - 1);
        const int h0 = n0 >> 6;  // 2 heads per 128-col tile
#pragma unroll
        for (int pass = 0; pass < 2; ++pass) {
            __syncthreads();  // SM free (K-loop or previous pass done)
            if (wm == pass) {
#pragma unroll
                for (int mt = 0; mt < 4; ++mt)
#pragma unroll
                    for (int nt = 0; nt < 4; ++nt)
#pragma unroll
                        for (int reg = 0; reg < 4; ++reg) {
                            const int r = mt * 16 + quad * 4 + reg;
                            const int cc = wn * 64 + nt * 16 + l16;
                            SM[r * 128 + cc] = f2bf(acc[mt][nt][reg] * qsc);
                        }
            }
            __syncthreads();
#pragma unroll
            for (int it = 0; it < 4; ++it) {
                const int cix = it * 256 + tid;
                const int r = cix >> 4, g = cix & 15;
                const int hh = g >> 3, d8 = g & 7;
                uint4 val = *(const uint4*)&SM[r * 128 + g * 8];
                *(uint4*)(dst + (((size_t)bb * NHEAD + h0 + hh) * SEQ +
                                 tok0 + pass * 64 + r) * HD + d8 * 8) = val;
            }
        }
    } else {
        // V^T epilogue: stage [d][m] in LDS (pad 136), then coalesced stores.
        const int bb = m0 >> 11, tok0 = m0 & (SEQ - 1);
#pragma unroll
        for (int pass = 0; pass < 2; ++pass) {
            __syncthreads();  // SM free (K-loop or previous pass done)
            if (wn == pass) {
#pragma unroll
                for (int mt = 0; mt < 4; ++mt)
#pragma unroll
                    for (int nt = 0; nt < 4; ++nt) {
                        const int d = nt * 16 + l16;
                        const int m = wm * 64 + mt * 16 + quad * 4;
                        uint2 w;
                        w.x = pk2bf(acc[mt][nt][0], acc[mt][nt][1]);
                        w.y = pk2bf(acc[mt][nt][2], acc[mt][nt][3]);
                        *(uint2*)&SM[d * 136 + m] = w;
                    }
            }
            __syncthreads();
            const int h = (n0 >> 6) + pass;
#pragma unroll
            for (int it = 0; it < 4; ++it) {
                const int c = it * 256 + tid;
                const int d = c >> 4, mc = (c & 15) * 8;
                uint4 val = *(const uint4*)&SM[d * 136 + mc];
                *(uint4*)(vt + (((size_t)bb * NHEAD + h) * HD + d) * SEQ + tok0 + mc) = val;
            }
        }
    }
}

// ---------------------------------------------------------------------------
// MFMA flash attention (causal), kt-SPLIT across waves, zero loop barriers.
// Grid (NHEAD, 32, BATCH), block 128 = 2 waves, one 64-row q-tile per block.
// Fixed-shift softmax is ADDITIVE (no max/rescale), so wave w independently
// accumulates O,l over kt ∈ {w, w+2, ...} — half the serial chain per wave,
// no __syncthreads in the loop (P round-trip is wave-private LDS; K/V are
// direct global loads, L2-pinned by h-first grid -> XCD locality).
// End: wave1 dumps O,l partials to LDS, one barrier, wave0 combines+stores.
// Ps is XOR-swizzled unpadded [64][64] per wave (R9-verified formulas).
// ---------------------------------------------------------------------------
__global__ __launch_bounds__(128) void attn_mfma(const unsigned short* __restrict__ Q,
                                                 const unsigned short* __restrict__ K,
                                                 const unsigned short* __restrict__ VT,
                                                 unsigned short* __restrict__ ctx) {
    __shared__ unsigned short Ps[2][4096];  // per-wave swizzled P (8 KB each)
    __shared__ float Ob[64][68];            // combine buffer (padded)
    __shared__ float Ls[64];                // combine row-sums
    const int tid = threadIdx.x;
    const int wave = tid >> 6, lane = tid & 63;
    const int quad = lane >> 4, l16 = lane & 15;
    const int h = blockIdx.x, b = blockIdx.z;
    const int p = 31 - (int)blockIdx.y;  // heavy-first
    const int row0 = p * 64;
    const unsigned short* Qp = Q + ((size_t)b * NHEAD + h) * SEQ * HD;
    const unsigned short* Kp = K + ((size_t)b * NHEAD + h) * SEQ * HD;
    const unsigned short* Vp = VT + ((size_t)b * NHEAD + h) * HD * SEQ;
    unsigned short* Pw = &Ps[wave][0];
    const int sw8 = l16 & 7;  // swizzle key (row & 7)

    bf16x8 bQ[4][2];  // Q as B-operand: [q-frag][ks]
#pragma unroll
    for (int f = 0; f < 4; ++f)
#pragma unroll
        for (int ks = 0; ks < 2; ++ks)
            bQ[f][ks] = *(const bf16x8*)(Qp +
                (size_t)(row0 + f * 16 + l16) * HD + ks * 32 + quad * 8);

    f32x4 o[4][4];    // O^T accumulators: [d-tile][q-frag]
    float ps[4] = {0.f, 0.f, 0.f, 0.f};
#pragma unroll
    for (int nt = 0; nt < 4; ++nt)
#pragma unroll
        for (int f = 0; f < 4; ++f)
            o[nt][f] = (f32x4){0.f, 0.f, 0.f, 0.f};

    for (int kt = wave; kt <= p; kt += 2) {
        // ---- K/V fragments (direct global; independent across iterations,
        //      compiler free to pipeline — no barriers anywhere in loop) ----
        bf16x8 aK[4][2], aV[4][2];
#pragma unroll
        for (int mt = 0; mt < 4; ++mt)
#pragma unroll
            for (int ks = 0; ks < 2; ++ks)
                aK[mt][ks] = *(const bf16x8*)(Kp +
                    (size_t)(kt * 64 + mt * 16 + l16) * HD + ks * 32 + quad * 8);
#pragma unroll
        for (int nt = 0; nt < 4; ++nt)
#pragma unroll
            for (int ks = 0; ks < 2; ++ks)
                aV[nt][ks] = *(const bf16x8*)(Vp +
                    (size_t)(nt * 16 + l16) * SEQ + kt * 64 + ks * 32 + quad * 8);

        // ---- S^T = K Q^T ----
        f32x4 sT[4][4];
#pragma unroll
        for (int mt = 0; mt < 4; ++mt)
#pragma unroll
            for (int f = 0; f < 4; ++f) {
                sT[mt][f] = __builtin_amdgcn_mfma_f32_16x16x32_bf16(
                    aK[mt][0], bQ[f][0], (f32x4){0.f, 0.f, 0.f, 0.f}, 0, 0, 0);
                sT[mt][f] = __builtin_amdgcn_mfma_f32_16x16x32_bf16(
                    aK[mt][1], bQ[f][1], sT[mt][f], 0, 0, 0);
            }

        // ---- exp2 + causal mask (diag tile only) + swizzled P write ----
        const bool diag = (kt == p);
#pragma unroll
        for (int mt = 0; mt < 4; ++mt)
#pragma unroll
            for (int f = 0; f < 4; ++f) {
                float pv[4];
#pragma unroll
                for (int reg = 0; reg < 4; ++reg)
                    pv[reg] = exp2f(sT[mt][f][reg]);
                if (diag) {
                    const int kb = kt * 64 + mt * 16 + quad * 4;
                    const int qg = row0 + f * 16 + l16;
#pragma unroll
                    for (int reg = 0; reg < 4; ++reg)
                        pv[reg] = (kb + reg > qg) ? 0.f : pv[reg];
                }
                ps[f] += (pv[0] + pv[1]) + (pv[2] + pv[3]);
                uint2 w;
                w.x = pk2bf(pv[0], pv[1]);
                w.y = pk2bf(pv[2], pv[3]);
                const int gph = ((mt * 2 + (quad >> 1)) ^ sw8);
                *(uint2*)&Pw[(f * 16 + l16) * 64 + gph * 8 + (quad & 1) * 4] = w;
            }

        // ---- P back in B-layout (wave-private; same-wave DS order) ----
        bf16x8 bP[4][2];
#pragma unroll
        for (int f = 0; f < 4; ++f)
#pragma unroll
            for (int ks = 0; ks < 2; ++ks)
                bP[f][ks] = *(const bf16x8*)&Pw[(f * 16 + l16) * 64 +
                                                ((ks * 4 + quad) ^ sw8) * 8];

        // ---- O^T += V^T P^T ----
#pragma unroll
        for (int nt = 0; nt < 4; ++nt)
#pragma unroll
            for (int f = 0; f < 4; ++f) {
                o[nt][f] = __builtin_amdgcn_mfma_f32_16x16x32_bf16(
                    aV[nt][0], bP[f][0], o[nt][f], 0, 0, 0);
                o[nt][f] = __builtin_amdgcn_mfma_f32_16x16x32_bf16(
                    aV[nt][1], bP[f][1], o[nt][f], 0, 0, 0);
            }
    }

    // ---- reduce ps across quads (q-row lives in l16; partials in quads) ----
#pragma unroll
    for (int f = 0; f < 4; ++f) {
        ps[f] += __shfl_xor(ps[f], 16);
        ps[f] += __shfl_xor(ps[f], 32);
    }

    // ---- cross-wave combine: wave1 -> LDS, barrier, wave0 adds+stores ----
    if (wave == 1) {
#pragma unroll
        for (int nt = 0; nt < 4; ++nt)
#pragma unroll
            for (int f = 0; f < 4; ++f)
                *(float4*)&Ob[f * 16 + l16][nt * 16 + quad * 4] =
                    *(float4*)&o[nt][f];
        if (quad == 0)
#pragma unroll
            for (int f = 0; f < 4; ++f)
                Ls[f * 16 + l16] = ps[f];
    }
    __syncthreads();
    if (wave == 0) {
        float inv[4];
#pragma unroll
        for (int f = 0; f < 4; ++f)
            inv[f] = 1.f / (ps[f] + Ls[f * 16 + l16]);
#pragma unroll
        for (int nt = 0; nt < 4; ++nt)
#pragma unroll
            for (int f = 0; f < 4; ++f) {
                float4 oo = *(float4*)&Ob[f * 16 + l16][nt * 16 + quad * 4];
                const int tok = row0 + f * 16 + l16;
                const int col = h * HD + nt * 16 + quad * 4;
                uint2 w;
                w.x = pk2bf((o[nt][f][0] + oo.x) * inv[f],
                            (o[nt][f][1] + oo.y) * inv[f]);
                w.y = pk2bf((o[nt][f][2] + oo.z) * inv[f],
                            (o[nt][f][3] + oo.w) * inv[f]);
                *(uint2*)(ctx + ((size_t)b * SEQ + tok) * D_MODEL + col) = w;
            }
    }
}

extern "C" void kernel_launch(void* const* d_in, const int* in_sizes, int n_in,
                              void* d_out, int out_size, void* d_ws, size_t ws_size,
                              hipStream_t stream) {
    const float* x  = (const float*)d_in[0];
    const float* Wq = (const float*)d_in[1];
    const float* Wk = (const float*)d_in[2];
    const float* Wv = (const float*)d_in[3];
    const float* Wo = (const float*)d_in[4];
    float* out = (float*)d_out;

    unsigned short* ws = (unsigned short*)d_ws;
    const size_t T = (size_t)MTOT * D_MODEL;  // 4,194,304 elements
    unsigned short* xb  = ws;                 // [4096,1024] bf16
    unsigned short* Wt  = ws + T;             // 4 x [1024,1024] bf16 (W^T)
    unsigned short* q   = ws + 2 * T;         // [B,H,N,64]  (pre-scaled)
    unsigned short* k   = ws + 3 * T;         // [B,H,N,64]
    unsigned short* vt  = ws + 4 * T;         // [B,H,64,N]
    unsigned short* ctx = ws + 5 * T;         // [4096,1024]

    prep<<<dim3(8192), dim3(256), 0, stream>>>(x, xb, Wq, Wk, Wv, Wo, Wt);

    gemm_mfma<0><<<dim3(8, 32, 3), dim3(256), 0, stream>>>(xb, Wt, q, k, vt, nullptr);

    attn_mfma<<<dim3(NHEAD, 32, BATCH), dim3(128), 0, stream>>>(q, k, vt, ctx);

    gemm_mfma<1><<<dim3(8, 32, 1), dim3(256), 0, stream>>>(ctx, Wt + 3 * (size_t)D_MODEL * D_MODEL,
                                                           nullptr, nullptr, nullptr, out);
}